// Round 8
// baseline (292.612 us; speedup 1.0000x reference)
//
#include <hip/hip_runtime.h>
#include <hip/hip_bf16.h>

// B=8, S=2048, C=512 single-head attention + residual, fp32 I/O.
// out = softmax(QK^T) V + x,  Q/K/V = x@W^T + b  (no 1/sqrt(dk)).
//
// Round 12 (v10 resubmit): previous round died with "MI355X container
// failed twice" = infra error, no kernel verdict. Kernel re-audited
// (barrier uniformity, buffer liveness, LDS attr, launch bounds, indexing)
// -- no defect found; resubmitting unchanged.
//
// v10: OCCUPANCY. v3-v9 all ran grid=256 (=CU count), 1 block/CU, 137KB
// LDS, 2 waves/SIMD -- every scheduling variant inside that budget was
// neutral or worse (v7 deep dbuf: neutral; v8 intra-wave: -5%; v9 wave
// spec: spilled). Counters: nothing saturated (MFMA 27, VALU 23, LDS ~50%,
// conflicts 16%) = latency-bound at low occupancy. v10 halves the block
// (QBLK=32, KVBLK=32, 64 kt) so LDS = 68.4KB -> 2 blocks/CU, grid 512,
// 16 waves/CU: block B's QK overlaps block A's PV + barrier drains
// structurally (m114 co-scheduling across blocks, no intra-block tricks).
//   - exact v3 two-barrier single-buffer loop at half scale
//   - waves 0-3: QK^T(16q x 16key) + softmax; all 8: PV (64-d slice each)
//   - o[] halves to 8 floatx4 (32 VGPR); __launch_bounds__(512,4) caps 128
//   - same swizzles; same key-order accumulation -> absmax-stable
//
// ws layout (total 68,687,872 B):
//   Wb    bf16 [1536][512]              @ 0
//   biasc f32  [1536]                   @ 1,572,864
//   Xb    bf16 [16384][512]             @ 1,579,008
//   Qb    bf16 [16384][512]             @ 18,356,224
//   Kb    bf16 [16384][512]             @ 35,133,440
//   Vt    bf16 [8][512][2048]           @ 51,910,656

typedef __bf16 bf16_t;
typedef bf16_t bf16x8 __attribute__((ext_vector_type(8)));
typedef float floatx4 __attribute__((ext_vector_type(4)));

#define MFMA16(a, b, c) __builtin_amdgcn_mfma_f32_16x16x32_bf16((a), (b), (c), 0, 0, 0)
// Ks 32768 + Vs 32768 + Ps 32*80=2560 + lpart 256
#define FLASH_LDS 68352

__device__ __forceinline__ void gload16(const void* g, void* l) {
    __builtin_amdgcn_global_load_lds((const __attribute__((address_space(1))) void*)g,
                                     (__attribute__((address_space(3))) void*)l, 16, 0, 0);
}

__device__ __forceinline__ float wave16_sum(float v) {
    v += __shfl_xor(v, 1);
    v += __shfl_xor(v, 2);
    v += __shfl_xor(v, 4);
    v += __shfl_xor(v, 8);
    return v;
}

// ---------------------------------------------------------------------------
// Kernel 1: convert X -> bf16 (blocks 0..4095), W/b -> bf16/f32 (4096..4863).
// ---------------------------------------------------------------------------
__global__ void convert_in(const float* __restrict__ X,
                           const float* __restrict__ Wq, const float* __restrict__ Wk,
                           const float* __restrict__ Wv, const float* __restrict__ bq,
                           const float* __restrict__ bk, const float* __restrict__ bv,
                           bf16_t* __restrict__ Xb, bf16_t* __restrict__ Wb,
                           float* __restrict__ biasc) {
    int bid = blockIdx.x, tid = threadIdx.x;
    if (bid < 4096) {
        size_t e0 = ((size_t)bid * 256 + tid) * 8;
        float4 f0 = *(const float4*)(X + e0);
        float4 f1 = *(const float4*)(X + e0 + 4);
        bf16x8 o;
        o[0] = (bf16_t)f0.x; o[1] = (bf16_t)f0.y; o[2] = (bf16_t)f0.z; o[3] = (bf16_t)f0.w;
        o[4] = (bf16_t)f1.x; o[5] = (bf16_t)f1.y; o[6] = (bf16_t)f1.z; o[7] = (bf16_t)f1.w;
        *(bf16x8*)(Xb + e0) = o;
    } else {
        int idx = (bid - 4096) * 256 + tid;       // [0, 196608)
        int e0 = idx * 4;
        int row = e0 >> 9, c = e0 & 511;
        const float* src;
        if (row < 512)       src = Wq + row * 512;
        else if (row < 1024) src = Wk + (row - 512) * 512;
        else                 src = Wv + (row - 1024) * 512;
        float4 v = *(const float4*)(src + c);
        Wb[e0 + 0] = (bf16_t)v.x;
        Wb[e0 + 1] = (bf16_t)v.y;
        Wb[e0 + 2] = (bf16_t)v.z;
        Wb[e0 + 3] = (bf16_t)v.w;
        if (idx < 1536) {
            float b;
            if (idx < 512)       b = bq[idx];
            else if (idx < 1024) b = bk[idx - 512];
            else                 b = bv[idx - 1024];
            biasc[idx] = b;
        }
    }
}

// ---------------------------------------------------------------------------
// Kernel 2: QKV GEMM, C[16384][1536] = Xb * Wb^T + bias. (unchanged, proven)
// ---------------------------------------------------------------------------
__global__ __launch_bounds__(256, 2)
void qkv_gemm(const bf16_t* __restrict__ Xb, const bf16_t* __restrict__ Wb,
              const float* __restrict__ biasc, bf16_t* __restrict__ Q,
              bf16_t* __restrict__ K, bf16_t* __restrict__ Vt) {
    __shared__ int4 smem4[2560];          // 40960 B
    char* As = (char*)smem4;              // 16384 B: 128 rows x 8 chunks(16B)
    char* Bs = (char*)smem4 + 16384;      // 16384 B
    char* Vtile = (char*)smem4;           // 33792 B (reused after barrier)

    const int tid = threadIdx.x;
    const int l = tid & 63, w = tid >> 6;
    const int lane16 = l & 15, lq = l >> 4;
    const int klo = lane16 & 7;
    const int m0 = (blockIdx.x & 127) << 7;
    const int n0 = (blockIdx.x >> 7) << 7;
    const int wm = (w >> 1) << 6, wn = (w & 1) << 6;
    const int srow = l >> 3;
    const int sc8 = (l & 7) ^ srow;

    floatx4 acc[4][4];
#pragma unroll
    for (int a = 0; a < 4; ++a)
#pragma unroll
        for (int bb = 0; bb < 4; ++bb) acc[a][bb] = (floatx4){0.f, 0.f, 0.f, 0.f};

    for (int it = 0; it < 8; ++it) {
        __syncthreads();
#pragma unroll
        for (int j = 0; j < 4; ++j) {
            int seg = j * 4 + w;
            int row = seg * 8 + srow;
            gload16(Xb + (size_t)(m0 + row) * 512 + it * 64 + sc8 * 8, As + seg * 1024);
            gload16(Wb + (size_t)(n0 + row) * 512 + it * 64 + sc8 * 8, Bs + seg * 1024);
        }
        __syncthreads();
#pragma unroll
        for (int kst = 0; kst < 2; ++kst) {
            bf16x8 afr[4], bfr[4];
#pragma unroll
            for (int mt = 0; mt < 4; ++mt)
                afr[mt] = *(const bf16x8*)(As + (wm + mt * 16 + lane16) * 128 +
                                           ((kst * 4 + lq) ^ klo) * 16);
#pragma unroll
            for (int nt = 0; nt < 4; ++nt)
                bfr[nt] = *(const bf16x8*)(Bs + (wn + nt * 16 + lane16) * 128 +
                                           ((kst * 4 + lq) ^ klo) * 16);
#pragma unroll
            for (int mt = 0; mt < 4; ++mt)
#pragma unroll
                for (int nt = 0; nt < 4; ++nt)
                    acc[mt][nt] = MFMA16(afr[mt], bfr[nt], acc[mt][nt]);
        }
    }

    float bias_v[4];
#pragma unroll
    for (int nt = 0; nt < 4; ++nt) bias_v[nt] = biasc[n0 + wn + nt * 16 + lane16];

    if (n0 < 1024) {
        bf16_t* Dst = (n0 < 512) ? Q : K;
        const int coff = (n0 < 512 ? n0 : n0 - 512) + wn;
#pragma unroll
        for (int mt = 0; mt < 4; ++mt)
#pragma unroll
            for (int nt = 0; nt < 4; ++nt)
#pragma unroll
                for (int i = 0; i < 4; ++i) {
                    int rowM = m0 + wm + mt * 16 + lq * 4 + i;
                    Dst[(size_t)rowM * 512 + coff + nt * 16 + lane16] =
                        (bf16_t)(acc[mt][nt][i] + bias_v[nt]);
                }
    } else {
        __syncthreads();
#pragma unroll
        for (int mt = 0; mt < 4; ++mt)
#pragma unroll
            for (int nt = 0; nt < 4; ++nt)
#pragma unroll
                for (int i = 0; i < 4; ++i) {
                    int dl = wn + nt * 16 + lane16;
                    int sl = wm + mt * 16 + lq * 4 + i;
                    *(bf16_t*)(Vtile + dl * 264 + sl * 2) =
                        (bf16_t)(acc[mt][nt][i] + bias_v[nt]);
                }
        __syncthreads();
        const int bb = m0 >> 11, s0 = m0 & 2047, dbase = n0 - 1024;
#pragma unroll
        for (int j = 0; j < 8; ++j) {
            int slot = j * 256 + tid;
            int dd = slot >> 4, c = slot & 15;
            *(int4*)(Vt + (size_t)(bb * 512 + dbase + dd) * 2048 + s0 + c * 8) =
                *(const int4*)(Vtile + dd * 264 + c * 16);
        }
    }
}

// ---------------------------------------------------------------------------
// Kernel 3: flash attention v10 + residual. 512 blocks (b = bid&7 -> XCD
// affinity), 512 threads = 8 waves, 2 blocks/CU (68.4KB LDS). Block = 32
// q-rows, KVBLK = 32 keys, 64 kt, v3's single-buffer two-barrier loop.
//  QK^T (waves 0-3): wave (qg = w>>1, h = w&1) -> S[16 q][16 keys], Q in
//        regs, K frags from swizzled LDS; softmax p=exp(s) -> Ps, lsum.
//  PV (all 8 waves): wave w owns d-slice w*64..+64 for ALL 32 q rows;
//        V frags from swizzled LDS; P read back as A-frags.
// ---------------------------------------------------------------------------
__global__ __launch_bounds__(512, 4)
void flash_attn_v10(const bf16_t* __restrict__ Q, const bf16_t* __restrict__ K,
                    const bf16_t* __restrict__ Vt, const float* __restrict__ X,
                    float* __restrict__ Out) {
    extern __shared__ char smem[];
    char* Ks = smem;                      // 32768: 32 keys x 64 chunks(16B), swz
    char* Vs = smem + 32768;              // 32768: 256 d-pairs x 8 slots(16B), swz
    char* Ps = smem + 65536;              // 2560: 32 rows x 80 B (64 data + 16 pad)
    float* lpart = (float*)(smem + 68096);   // 32 rows x 2 halves

    const int tid = threadIdx.x;
    const int l = tid & 63, w = tid >> 6;
    const int lane16 = l & 15, lq = l >> 4;
    const int qg = w >> 1, h = w & 1;          // QK^T role (waves 0-3)
    const int dbase = w << 6;                  // PV d-slice
    const int b = blockIdx.x & 7;
    const int q0 = (blockIdx.x >> 3) << 5;     // 64 q-tiles of 32 per batch

    const bf16_t* Kbase = K + (size_t)b * 2048 * 512;
    const bf16_t* Vbase = Vt + (size_t)b * 512 * 2048;

    // per-lane staging constants (v7-proven layouts at 32-key scale)
    const int dl_v = ((l >> 3) << 1) | ((l & 7) >> 2);   // within-seg d offset
    const int vc   = (l & 3) ^ ((l >> 3) & 3);           // source chunk for V

    auto stageK = [&](int kt) {
#pragma unroll
        for (int j = 0; j < 4; ++j) {
            int seg = j * 8 + w;                          // key 0..31
            int c = (l & ~7) | ((l & 7) ^ (seg & 7));
            gload16(Kbase + ((size_t)kt * 32 + seg) * 512 + c * 8, Ks + seg * 1024);
        }
    };
    auto stageV = [&](int kt) {
        const bf16_t* Vsrc = Vbase + kt * 32;
#pragma unroll
        for (int j = 0; j < 4; ++j) {
            int seg = j * 8 + w;
            int d = seg * 16 + dl_v;
            gload16(Vsrc + (size_t)d * 2048 + vc * 8, Vs + seg * 1024);
        }
    };

    stageK(0);

    // Q fragments (waves 0-3): A[m=lane16][k=lq*8+...] rows q0+qg*16..+16
    bf16x8 qf[16];
    if (w < 4) {
        const bf16_t* Qrow =
            Q + (size_t)(b * 2048 + q0 + qg * 16 + lane16) * 512 + lq * 8;
#pragma unroll
        for (int kst = 0; kst < 16; ++kst) qf[kst] = *(const bf16x8*)(Qrow + kst * 32);
    }

    floatx4 o[8];                      // [qgi][dg]: rows qgi*16.., cols dbase+dg*16..
#pragma unroll
    for (int t = 0; t < 8; ++t) o[t] = (floatx4){0.f, 0.f, 0.f, 0.f};
    float lsum[4] = {0.f, 0.f, 0.f, 0.f};   // per-lane partial row sums (waves 0-3)
    const float L2E = 1.4426950408889634f;
    const int key = h * 16 + lane16;         // QK key column (waves 0-3)
    const int prow = qg * 16 + lq * 4;       // softmax row base (waves 0-3)

    __syncthreads();   // K_0 staged

    for (int kt = 0; kt < 64; ++kt) {
        // stage V_kt (overlaps QK^T; drained by barrier 1)
        stageV(kt);

        // ---- QK^T: 16 q rows x 16 keys, k=512 (waves 0-3) ----
        if (w < 4) {
            floatx4 sc = (floatx4){0.f, 0.f, 0.f, 0.f};
#pragma unroll
            for (int kst = 0; kst < 16; ++kst) {
                int i0 = kst * 4 + lq;
                int p0 = (i0 & ~7) | ((i0 & 7) ^ (key & 7));
                bf16x8 kb = *(const bf16x8*)(Ks + key * 1024 + p0 * 16);
                sc = MFMA16(qf[kst], kb, sc);
            }
            // ---- softmax (no max shift): p = exp(s), write P, accum l ----
#pragma unroll
            for (int i = 0; i < 4; ++i) {
                float p = __builtin_exp2f(sc[i] * L2E);
                lsum[i] += p;
                *(bf16_t*)(Ps + (prow + i) * 80 + key * 2) = (bf16_t)p;
            }
        }
        __syncthreads();   // barrier 1: V_kt staged, P visible, Ks free

        // stage K_{kt+1} (overlaps PV; drained by barrier 2)
        if (kt < 63) stageK(kt + 1);

        // ---- PV: O[32 q x 64 d slice] += P[32x32] * V^T (all 8 waves) ----
        {
            bf16x8 pa[2], vb[4];
#pragma unroll
            for (int qgi = 0; qgi < 2; ++qgi)
                pa[qgi] = *(const bf16x8*)(Ps + (qgi * 16 + lane16) * 80 + lq * 16);
#pragma unroll
            for (int dg = 0; dg < 4; ++dg) {
                int d = dbase + dg * 16 + lane16;
                int slot = (d & 1) * 4 + (lq ^ ((d >> 1) & 3));
                vb[dg] = *(const bf16x8*)(Vs + (d >> 1) * 128 + slot * 16);
            }
#pragma unroll
            for (int dg = 0; dg < 4; ++dg)
#pragma unroll
                for (int qgi = 0; qgi < 2; ++qgi)
                    o[qgi * 4 + dg] = MFMA16(pa[qgi], vb[dg], o[qgi * 4 + dg]);
        }
        __syncthreads();   // barrier 2: K_{kt+1} staged, Vs/Ps free
    }

    // epilogue: waves 0-3 publish row sums; all waves normalize + residual
    if (w < 4) {
#pragma unroll
        for (int i = 0; i < 4; ++i) {
            float s = wave16_sum(lsum[i]);
            if (lane16 == 0) lpart[(prow + i) * 2 + h] = s;
        }
    }
    __syncthreads();

#pragma unroll
    for (int qgi = 0; qgi < 2; ++qgi) {
        float rinv[4];
#pragma unroll
        for (int i = 0; i < 4; ++i) {
            int row = qgi * 16 + lq * 4 + i;
            rinv[i] = 1.0f / (lpart[row * 2] + lpart[row * 2 + 1]);
        }
#pragma unroll
        for (int dg = 0; dg < 4; ++dg) {
            int d = dbase + dg * 16 + lane16;
#pragma unroll
            for (int i = 0; i < 4; ++i) {
                int row = q0 + qgi * 16 + lq * 4 + i;
                size_t g = (size_t)(b * 2048 + row) * 512 + d;
                Out[g] = o[qgi * 4 + dg][i] * rinv[i] + X[g];
            }
        }
    }
}

// ---------------------------------------------------------------------------
extern "C" void kernel_launch(void* const* d_in, const int* in_sizes, int n_in,
                              void* d_out, int out_size, void* d_ws, size_t ws_size,
                              hipStream_t stream) {
    const float* x  = (const float*)d_in[0];
    const float* Wq = (const float*)d_in[1];
    const float* bq = (const float*)d_in[2];
    const float* Wk = (const float*)d_in[3];
    const float* bk = (const float*)d_in[4];
    const float* Wv = (const float*)d_in[5];
    const float* bv = (const float*)d_in[6];
    float* out = (float*)d_out;
    char* ws = (char*)d_ws;

    bf16_t* Wb    = (bf16_t*)(ws);
    float*  biasc = (float*)(ws + 1572864);
    bf16_t* Xb    = (bf16_t*)(ws + 1579008);
    bf16_t* Qb    = (bf16_t*)(ws + 18356224);
    bf16_t* Kb    = (bf16_t*)(ws + 35133440);
    bf16_t* Vt    = (bf16_t*)(ws + 51910656);
    // total ws use: 68,687,872 B

    convert_in<<<4864, 256, 0, stream>>>(x, Wq, Wk, Wv, bq, bk, bv, Xb, Wb, biasc);
    qkv_gemm<<<1536, 256, 0, stream>>>(Xb, Wb, biasc, Qb, Kb, Vt);

    hipFuncSetAttribute(reinterpret_cast<const void*>(flash_attn_v10),
                        hipFuncAttributeMaxDynamicSharedMemorySize, FLASH_LDS);
    flash_attn_v10<<<512, 512, FLASH_LDS, stream>>>(Qb, Kb, Vt, x, out);
}

// Round 9
// 244.098 us; speedup vs baseline: 1.1987x; 1.1987x over previous
//
#include <hip/hip_runtime.h>
#include <hip/hip_bf16.h>

// B=8, S=2048, C=512 single-head attention + residual, fp32 I/O.
// out = softmax(QK^T) V + x,  Q/K/V = x@W^T + b  (no 1/sqrt(dk)).
//
// Round 13 (v11): v5 re-run WITHOUT the spill confound. Post-mortem chain:
// v5 (32q x 16key QK role, halves K-frag LDS reads) regressed only because
// the compiler chose 128 VGPR (dynamic LDS hides the 1-block/CU limit, so
// it targeted 4 waves/EU) and spilled qf[2][16] to scratch (WRITE +17MB).
// v10 confirmed the same artifact at (512,4). Fix: pin the allocator to
// the occupancy LDS already dictates via amdgpu_waves_per_eu(2,2) ->
// 256 VGPR budget; qf 128 + o 64 + temps ~40 fits, zero spill.
//   - QK^T wave role 32q x 16keys: each K B-frag ds_read_b128 feeds TWO
//     MFMAs -> K-frag LDS reads halve (256 -> 128 KB/kt/CU), the largest
//     LDS-pipe consumer (~77% busy incl. conflicts). v5 measured conflicts
//     1.049e7 -> 6.29e6 with this shape.
//   - everything else byte-identical to v3/v5 (proven absmax 0.109375).
//
// ws layout (total 68,687,872 B):
//   Wb    bf16 [1536][512]              @ 0
//   biasc f32  [1536]                   @ 1,572,864
//   Xb    bf16 [16384][512]             @ 1,579,008
//   Qb    bf16 [16384][512]             @ 18,356,224
//   Kb    bf16 [16384][512]             @ 35,133,440
//   Vt    bf16 [8][512][2048]           @ 51,910,656

typedef __bf16 bf16_t;
typedef bf16_t bf16x8 __attribute__((ext_vector_type(8)));
typedef float floatx4 __attribute__((ext_vector_type(4)));

#define MFMA16(a, b, c) __builtin_amdgcn_mfma_f32_16x16x32_bf16((a), (b), (c), 0, 0, 0)
// Ks 65536 + Vs 65536 + Ps 64*144=9216 + lpart 64*4*4=1024
#define FLASH_LDS 141312

__device__ __forceinline__ void gload16(const void* g, void* l) {
    __builtin_amdgcn_global_load_lds((const __attribute__((address_space(1))) void*)g,
                                     (__attribute__((address_space(3))) void*)l, 16, 0, 0);
}

__device__ __forceinline__ float wave16_sum(float v) {
    v += __shfl_xor(v, 1);
    v += __shfl_xor(v, 2);
    v += __shfl_xor(v, 4);
    v += __shfl_xor(v, 8);
    return v;
}

// ---------------------------------------------------------------------------
// Kernel 1: convert X -> bf16 (blocks 0..4095), W/b -> bf16/f32 (4096..4863).
// ---------------------------------------------------------------------------
__global__ void convert_in(const float* __restrict__ X,
                           const float* __restrict__ Wq, const float* __restrict__ Wk,
                           const float* __restrict__ Wv, const float* __restrict__ bq,
                           const float* __restrict__ bk, const float* __restrict__ bv,
                           bf16_t* __restrict__ Xb, bf16_t* __restrict__ Wb,
                           float* __restrict__ biasc) {
    int bid = blockIdx.x, tid = threadIdx.x;
    if (bid < 4096) {
        size_t e0 = ((size_t)bid * 256 + tid) * 8;
        float4 f0 = *(const float4*)(X + e0);
        float4 f1 = *(const float4*)(X + e0 + 4);
        bf16x8 o;
        o[0] = (bf16_t)f0.x; o[1] = (bf16_t)f0.y; o[2] = (bf16_t)f0.z; o[3] = (bf16_t)f0.w;
        o[4] = (bf16_t)f1.x; o[5] = (bf16_t)f1.y; o[6] = (bf16_t)f1.z; o[7] = (bf16_t)f1.w;
        *(bf16x8*)(Xb + e0) = o;
    } else {
        int idx = (bid - 4096) * 256 + tid;       // [0, 196608)
        int e0 = idx * 4;
        int row = e0 >> 9, c = e0 & 511;
        const float* src;
        if (row < 512)       src = Wq + row * 512;
        else if (row < 1024) src = Wk + (row - 512) * 512;
        else                 src = Wv + (row - 1024) * 512;
        float4 v = *(const float4*)(src + c);
        Wb[e0 + 0] = (bf16_t)v.x;
        Wb[e0 + 1] = (bf16_t)v.y;
        Wb[e0 + 2] = (bf16_t)v.z;
        Wb[e0 + 3] = (bf16_t)v.w;
        if (idx < 1536) {
            float b;
            if (idx < 512)       b = bq[idx];
            else if (idx < 1024) b = bk[idx - 512];
            else                 b = bv[idx - 1024];
            biasc[idx] = b;
        }
    }
}

// ---------------------------------------------------------------------------
// Kernel 2: QKV GEMM, C[16384][1536] = Xb * Wb^T + bias. (unchanged, proven)
// ---------------------------------------------------------------------------
__global__ __launch_bounds__(256, 2)
void qkv_gemm(const bf16_t* __restrict__ Xb, const bf16_t* __restrict__ Wb,
              const float* __restrict__ biasc, bf16_t* __restrict__ Q,
              bf16_t* __restrict__ K, bf16_t* __restrict__ Vt) {
    __shared__ int4 smem4[2560];          // 40960 B
    char* As = (char*)smem4;              // 16384 B: 128 rows x 8 chunks(16B)
    char* Bs = (char*)smem4 + 16384;      // 16384 B
    char* Vtile = (char*)smem4;           // 33792 B (reused after barrier)

    const int tid = threadIdx.x;
    const int l = tid & 63, w = tid >> 6;
    const int lane16 = l & 15, lq = l >> 4;
    const int klo = lane16 & 7;
    const int m0 = (blockIdx.x & 127) << 7;
    const int n0 = (blockIdx.x >> 7) << 7;
    const int wm = (w >> 1) << 6, wn = (w & 1) << 6;
    const int srow = l >> 3;
    const int sc8 = (l & 7) ^ srow;

    floatx4 acc[4][4];
#pragma unroll
    for (int a = 0; a < 4; ++a)
#pragma unroll
        for (int bb = 0; bb < 4; ++bb) acc[a][bb] = (floatx4){0.f, 0.f, 0.f, 0.f};

    for (int it = 0; it < 8; ++it) {
        __syncthreads();
#pragma unroll
        for (int j = 0; j < 4; ++j) {
            int seg = j * 4 + w;
            int row = seg * 8 + srow;
            gload16(Xb + (size_t)(m0 + row) * 512 + it * 64 + sc8 * 8, As + seg * 1024);
            gload16(Wb + (size_t)(n0 + row) * 512 + it * 64 + sc8 * 8, Bs + seg * 1024);
        }
        __syncthreads();
#pragma unroll
        for (int kst = 0; kst < 2; ++kst) {
            bf16x8 afr[4], bfr[4];
#pragma unroll
            for (int mt = 0; mt < 4; ++mt)
                afr[mt] = *(const bf16x8*)(As + (wm + mt * 16 + lane16) * 128 +
                                           ((kst * 4 + lq) ^ klo) * 16);
#pragma unroll
            for (int nt = 0; nt < 4; ++nt)
                bfr[nt] = *(const bf16x8*)(Bs + (wn + nt * 16 + lane16) * 128 +
                                           ((kst * 4 + lq) ^ klo) * 16);
#pragma unroll
            for (int mt = 0; mt < 4; ++mt)
#pragma unroll
                for (int nt = 0; nt < 4; ++nt)
                    acc[mt][nt] = MFMA16(afr[mt], bfr[nt], acc[mt][nt]);
        }
    }

    float bias_v[4];
#pragma unroll
    for (int nt = 0; nt < 4; ++nt) bias_v[nt] = biasc[n0 + wn + nt * 16 + lane16];

    if (n0 < 1024) {
        bf16_t* Dst = (n0 < 512) ? Q : K;
        const int coff = (n0 < 512 ? n0 : n0 - 512) + wn;
#pragma unroll
        for (int mt = 0; mt < 4; ++mt)
#pragma unroll
            for (int nt = 0; nt < 4; ++nt)
#pragma unroll
                for (int i = 0; i < 4; ++i) {
                    int rowM = m0 + wm + mt * 16 + lq * 4 + i;
                    Dst[(size_t)rowM * 512 + coff + nt * 16 + lane16] =
                        (bf16_t)(acc[mt][nt][i] + bias_v[nt]);
                }
    } else {
        __syncthreads();
#pragma unroll
        for (int mt = 0; mt < 4; ++mt)
#pragma unroll
            for (int nt = 0; nt < 4; ++nt)
#pragma unroll
                for (int i = 0; i < 4; ++i) {
                    int dl = wn + nt * 16 + lane16;
                    int sl = wm + mt * 16 + lq * 4 + i;
                    *(bf16_t*)(Vtile + dl * 264 + sl * 2) =
                        (bf16_t)(acc[mt][nt][i] + bias_v[nt]);
                }
        __syncthreads();
        const int bb = m0 >> 11, s0 = m0 & 2047, dbase = n0 - 1024;
#pragma unroll
        for (int j = 0; j < 8; ++j) {
            int slot = j * 256 + tid;
            int dd = slot >> 4, c = slot & 15;
            *(int4*)(Vt + (size_t)(bb * 512 + dbase + dd) * 2048 + s0 + c * 8) =
                *(const int4*)(Vtile + dd * 264 + c * 16);
        }
    }
}

// ---------------------------------------------------------------------------
// Kernel 3: flash attention v11 + residual. 256 blocks (b = bid&7 -> XCD
// affinity), 512 threads = 8 waves. Block = 64 q-rows. v3 sync structure.
//  QK^T: wave (qg2 = w>>2, h2 = w&3) computes S[32 q][16 keys]: Q in regs
//        (2 row-groups of 16), ONE K frag read feeds TWO MFMAs.
//  softmax: p = exp(s) (no max shift), P -> LDS (144 B row stride: 128 data
//        + 16 pad; row-pair aliasing is 2-way = free), l = running sum.
//  PV:   wave w owns d-slice w*64..+64 for ALL 64 q rows; V frags reused
//        across 4 q-groups; P read back as A-frags from LDS.
//  amdgpu_waves_per_eu(2,2): pin regalloc to the 2-waves/SIMD the 141KB
//  LDS already dictates -> 256 VGPR budget, no heuristic spill (v5 bug).
// ---------------------------------------------------------------------------
__global__ __launch_bounds__(512)
__attribute__((amdgpu_waves_per_eu(2, 2)))
void flash_attn_v11(const bf16_t* __restrict__ Q, const bf16_t* __restrict__ K,
                    const bf16_t* __restrict__ Vt, const float* __restrict__ X,
                    float* __restrict__ Out) {
    extern __shared__ char smem[];
    char* Ks = smem;                   // 65536: 64 keys x 64 chunks(16B), swizzled
    char* Vs = smem + 65536;           // 65536: 512 d x 8 chunks(16B), swizzled
    char* Ps = smem + 131072;          // 9216: 64 rows x 144 B (128 data + 16 pad)
    float* lpart = (float*)(smem + 140288);   // 64 rows x 4 key-quarters

    const int tid = threadIdx.x;
    const int l = tid & 63, w = tid >> 6;
    const int lane16 = l & 15, lq = l >> 4;
    const int qg2 = w >> 2, h2 = w & 3;        // QK^T role: 32 q x 16 keys
    const int dbase = w << 6;                  // PV d-slice
    const int b = blockIdx.x & 7;
    const int q0 = (blockIdx.x >> 3) << 6;

    const bf16_t* Kbase = K + (size_t)b * 2048 * 512;
    const bf16_t* Vbase = Vt + (size_t)b * 512 * 2048;

    // stage K_0: 64 segs (keys) x 1KB, 8 per wave, source-chunk swizzle ^seg
#pragma unroll
    for (int j = 0; j < 8; ++j) {
        int seg = j * 8 + w;
        int c = (l & ~7) | ((l & 7) ^ (seg & 7));
        gload16(Kbase + (size_t)seg * 512 + c * 8, Ks + seg * 1024);
    }

    // Q fragments: A[m=lane16][k=lq*8+...] for row-groups qg2*32 and +16
    bf16x8 qf[2][16];
#pragma unroll
    for (int qgi = 0; qgi < 2; ++qgi) {
        const bf16_t* Qrow =
            Q + (size_t)(b * 2048 + q0 + qg2 * 32 + qgi * 16 + lane16) * 512 + lq * 8;
#pragma unroll
        for (int kst = 0; kst < 16; ++kst) qf[qgi][kst] = *(const bf16x8*)(Qrow + kst * 32);
    }

    floatx4 o[16];                     // [qgi][dg]: rows qgi*16.., cols dbase+dg*16..
#pragma unroll
    for (int t = 0; t < 16; ++t) o[t] = (floatx4){0.f, 0.f, 0.f, 0.f};
    float lsum[8];                     // [qgi*4+i] per-lane partial row sums
#pragma unroll
    for (int t = 0; t < 8; ++t) lsum[t] = 0.f;
    const float L2E = 1.4426950408889634f;

    __syncthreads();   // K_0 staged

    for (int kt = 0; kt < 32; ++kt) {
        // issue V_kt staging (overlaps QK^T): 64 segs x (8 d x 8 key-chunks)
        {
            const bf16_t* Vsrc = Vbase + kt * 64;
#pragma unroll
            for (int j = 0; j < 8; ++j) {
                int seg = j * 8 + w;
                int d = seg * 8 + (l >> 3);
                int c = (l & 7) ^ (l >> 3);
                gload16(Vsrc + (size_t)d * 2048 + c * 8, Vs + seg * 1024);
            }
        }
        // ---- QK^T: 32 q rows x 16 keys (this wave's quarter), k=512 ----
        // ONE kb read per kst feeds both q-groups.
        floatx4 sc[2];
        sc[0] = (floatx4){0.f, 0.f, 0.f, 0.f};
        sc[1] = (floatx4){0.f, 0.f, 0.f, 0.f};
        const int key = h2 * 16 + lane16;
#pragma unroll
        for (int kst = 0; kst < 16; ++kst) {
            int i0 = kst * 4 + lq;
            int p0 = (i0 & ~7) | ((i0 & 7) ^ (key & 7));
            bf16x8 kb = *(const bf16x8*)(Ks + key * 1024 + p0 * 16);
            sc[0] = MFMA16(qf[0][kst], kb, sc[0]);
            sc[1] = MFMA16(qf[1][kst], kb, sc[1]);
        }
        // ---- softmax (no max shift): p = exp(s), write P, accumulate l ----
#pragma unroll
        for (int qgi = 0; qgi < 2; ++qgi) {
#pragma unroll
            for (int i = 0; i < 4; ++i) {
                int row = qg2 * 32 + qgi * 16 + lq * 4 + i;
                float p = __builtin_exp2f(sc[qgi][i] * L2E);
                lsum[qgi * 4 + i] += p;
                *(bf16_t*)(Ps + row * 144 + key * 2) = (bf16_t)p;
            }
        }
        __syncthreads();   // barrier 1: V_kt staged, P visible, Ks free

        // issue K_{kt+1} staging (overlaps PV)
        if (kt < 31) {
            const bf16_t* Ksrc = Kbase + (size_t)(kt + 1) * 64 * 512;
#pragma unroll
            for (int j = 0; j < 8; ++j) {
                int seg = j * 8 + w;
                int c = (l & ~7) | ((l & 7) ^ (seg & 7));
                gload16(Ksrc + (size_t)seg * 512 + c * 8, Ks + seg * 1024);
            }
        }
        // ---- PV: O[64 q x 64 d slice] += P[64x64] * V^T ----
#pragma unroll
        for (int kk = 0; kk < 2; ++kk) {
            bf16x8 pa[4];
#pragma unroll
            for (int qgi = 0; qgi < 4; ++qgi)
                pa[qgi] = *(const bf16x8*)(Ps + (qgi * 16 + lane16) * 144 + kk * 64 + lq * 16);
#pragma unroll
            for (int dg = 0; dg < 4; ++dg) {
                int d = dbase + dg * 16 + lane16;
                int pos = (kk * 4 + lq) ^ (d & 7);
                bf16x8 vb = *(const bf16x8*)(Vs + d * 128 + pos * 16);
#pragma unroll
                for (int qgi = 0; qgi < 4; ++qgi)
                    o[qgi * 4 + dg] = MFMA16(pa[qgi], vb, o[qgi * 4 + dg]);
            }
        }
        __syncthreads();   // barrier 2: K_{kt+1} staged, Vs/Ps free
    }

    // epilogue: reduce l across lane16, publish per-key-quarter partials,
    // normalize, + residual
#pragma unroll
    for (int qgi = 0; qgi < 2; ++qgi)
#pragma unroll
        for (int i = 0; i < 4; ++i) {
            float s = wave16_sum(lsum[qgi * 4 + i]);
            if (lane16 == 0)
                lpart[(qg2 * 32 + qgi * 16 + lq * 4 + i) * 4 + h2] = s;
        }
    __syncthreads();

#pragma unroll
    for (int qgi = 0; qgi < 4; ++qgi) {
        float rinv[4];
#pragma unroll
        for (int i = 0; i < 4; ++i) {
            int row = qgi * 16 + lq * 4 + i;
            rinv[i] = 1.0f / (lpart[row * 4] + lpart[row * 4 + 1] +
                              lpart[row * 4 + 2] + lpart[row * 4 + 3]);
        }
#pragma unroll
        for (int dg = 0; dg < 4; ++dg) {
            int d = dbase + dg * 16 + lane16;
#pragma unroll
            for (int i = 0; i < 4; ++i) {
                int row = q0 + qgi * 16 + lq * 4 + i;
                size_t g = (size_t)(b * 2048 + row) * 512 + d;
                Out[g] = o[qgi * 4 + dg][i] * rinv[i] + X[g];
            }
        }
    }
}

// ---------------------------------------------------------------------------
extern "C" void kernel_launch(void* const* d_in, const int* in_sizes, int n_in,
                              void* d_out, int out_size, void* d_ws, size_t ws_size,
                              hipStream_t stream) {
    const float* x  = (const float*)d_in[0];
    const float* Wq = (const float*)d_in[1];
    const float* bq = (const float*)d_in[2];
    const float* Wk = (const float*)d_in[3];
    const float* bk = (const float*)d_in[4];
    const float* Wv = (const float*)d_in[5];
    const float* bv = (const float*)d_in[6];
    float* out = (float*)d_out;
    char* ws = (char*)d_ws;

    bf16_t* Wb    = (bf16_t*)(ws);
    float*  biasc = (float*)(ws + 1572864);
    bf16_t* Xb    = (bf16_t*)(ws + 1579008);
    bf16_t* Qb    = (bf16_t*)(ws + 18356224);
    bf16_t* Kb    = (bf16_t*)(ws + 35133440);
    bf16_t* Vt    = (bf16_t*)(ws + 51910656);
    // total ws use: 68,687,872 B

    convert_in<<<4864, 256, 0, stream>>>(x, Wq, Wk, Wv, bq, bk, bv, Xb, Wb, biasc);
    qkv_gemm<<<1536, 256, 0, stream>>>(Xb, Wb, biasc, Qb, Kb, Vt);

    hipFuncSetAttribute(reinterpret_cast<const void*>(flash_attn_v11),
                        hipFuncAttributeMaxDynamicSharedMemorySize, FLASH_LDS);
    flash_attn_v11<<<256, 512, FLASH_LDS, stream>>>(Qb, Kb, Vt, x, out);
}

// Round 10
// 215.512 us; speedup vs baseline: 1.3578x; 1.1326x over previous
//
#include <hip/hip_runtime.h>
#include <hip/hip_bf16.h>

// B=8, S=2048, C=512 single-head attention + residual, fp32 I/O.
// out = softmax(QK^T) V + x,  Q/K/V = x@W^T + b  (no 1/sqrt(dk)).
//
// Round 14 (v12): flash kept at v7 (the measured floor: ~107us; v4/v6
// traffic, v8 scheduling, v9 specialization, v10 occupancy, v5/v11
// register-shape all regressed or neutral -- compiler hard-caps 128 VGPR
// and spills anything larger). NEW TARGET: qkv_gemm. Best-total run
// (221.5us) had flash=107.8 -> ~114us in convert+gemm+gaps for only
// 25.8 GFLOP. Its K-loop was {sync; issue gload_lds; sync(=vmcnt0 drain);
// compute}: every iteration exposed the FULL L2->LDS DMA latency with
// zero cover. v12 double-buffers A/B tiles with the proven
// issue-before-compute pattern (one sync/iter, stage(it+1) covered by
// compute(it) + co-resident block):
//   stage(0); sync; for it { if(it<7) stage(it+1)->buf^1; compute(buf); sync; }
// LDS 64KB (2x32KB buffers; epilogue Vtile aliases them after final sync),
// still 2 blocks/CU. Accumulation order identical -> absmax-stable.
//
// ws layout (total 68,687,872 B):
//   Wb    bf16 [1536][512]              @ 0
//   biasc f32  [1536]                   @ 1,572,864
//   Xb    bf16 [16384][512]             @ 1,579,008
//   Qb    bf16 [16384][512]             @ 18,356,224
//   Kb    bf16 [16384][512]             @ 35,133,440
//   Vt    bf16 [8][512][2048]           @ 51,910,656

typedef __bf16 bf16_t;
typedef bf16_t bf16x8 __attribute__((ext_vector_type(8)));
typedef float floatx4 __attribute__((ext_vector_type(4)));

#define MFMA16(a, b, c) __builtin_amdgcn_mfma_f32_16x16x32_bf16((a), (b), (c), 0, 0, 0)
// Ks dbuf 2*32768 + Vs dbuf 2*32768 + Ps 64*80=5120 + lpart 512
#define FLASH_LDS 136704

__device__ __forceinline__ void gload16(const void* g, void* l) {
    __builtin_amdgcn_global_load_lds((const __attribute__((address_space(1))) void*)g,
                                     (__attribute__((address_space(3))) void*)l, 16, 0, 0);
}

__device__ __forceinline__ float wave16_sum(float v) {
    v += __shfl_xor(v, 1);
    v += __shfl_xor(v, 2);
    v += __shfl_xor(v, 4);
    v += __shfl_xor(v, 8);
    return v;
}

// ---------------------------------------------------------------------------
// Kernel 1: convert X -> bf16 (blocks 0..4095), W/b -> bf16/f32 (4096..4863).
// ---------------------------------------------------------------------------
__global__ void convert_in(const float* __restrict__ X,
                           const float* __restrict__ Wq, const float* __restrict__ Wk,
                           const float* __restrict__ Wv, const float* __restrict__ bq,
                           const float* __restrict__ bk, const float* __restrict__ bv,
                           bf16_t* __restrict__ Xb, bf16_t* __restrict__ Wb,
                           float* __restrict__ biasc) {
    int bid = blockIdx.x, tid = threadIdx.x;
    if (bid < 4096) {
        size_t e0 = ((size_t)bid * 256 + tid) * 8;
        float4 f0 = *(const float4*)(X + e0);
        float4 f1 = *(const float4*)(X + e0 + 4);
        bf16x8 o;
        o[0] = (bf16_t)f0.x; o[1] = (bf16_t)f0.y; o[2] = (bf16_t)f0.z; o[3] = (bf16_t)f0.w;
        o[4] = (bf16_t)f1.x; o[5] = (bf16_t)f1.y; o[6] = (bf16_t)f1.z; o[7] = (bf16_t)f1.w;
        *(bf16x8*)(Xb + e0) = o;
    } else {
        int idx = (bid - 4096) * 256 + tid;       // [0, 196608)
        int e0 = idx * 4;
        int row = e0 >> 9, c = e0 & 511;
        const float* src;
        if (row < 512)       src = Wq + row * 512;
        else if (row < 1024) src = Wk + (row - 512) * 512;
        else                 src = Wv + (row - 1024) * 512;
        float4 v = *(const float4*)(src + c);
        Wb[e0 + 0] = (bf16_t)v.x;
        Wb[e0 + 1] = (bf16_t)v.y;
        Wb[e0 + 2] = (bf16_t)v.z;
        Wb[e0 + 3] = (bf16_t)v.w;
        if (idx < 1536) {
            float b;
            if (idx < 512)       b = bq[idx];
            else if (idx < 1024) b = bk[idx - 512];
            else                 b = bv[idx - 1024];
            biasc[idx] = b;
        }
    }
}

// ---------------------------------------------------------------------------
// Kernel 2: QKV GEMM, C[16384][1536] = Xb * Wb^T + bias.
// v12: double-buffered staging, one sync per K-iteration.
// ---------------------------------------------------------------------------
__global__ __launch_bounds__(256, 2)
void qkv_gemm(const bf16_t* __restrict__ Xb, const bf16_t* __restrict__ Wb,
              const float* __restrict__ biasc, bf16_t* __restrict__ Q,
              bf16_t* __restrict__ K, bf16_t* __restrict__ Vt) {
    __shared__ int4 smem4[4096];          // 65536 B: 2 x (As 16K + Bs 16K)
    char* base = (char*)smem4;
    char* Vtile = (char*)smem4;           // 33792 B epilogue reuse (after final sync)

    const int tid = threadIdx.x;
    const int l = tid & 63, w = tid >> 6;
    const int lane16 = l & 15, lq = l >> 4;
    const int klo = lane16 & 7;
    const int m0 = (blockIdx.x & 127) << 7;
    const int n0 = (blockIdx.x >> 7) << 7;
    const int wm = (w >> 1) << 6, wn = (w & 1) << 6;
    const int srow = l >> 3;
    const int sc8 = (l & 7) ^ srow;

    // stage A/B tiles for K-step `it` into buffer `buf` (As 16K + Bs 16K)
    auto stage = [&](int it, int buf) {
        char* As = base + buf * 32768;
        char* Bs = As + 16384;
#pragma unroll
        for (int j = 0; j < 4; ++j) {
            int seg = j * 4 + w;
            int row = seg * 8 + srow;
            gload16(Xb + (size_t)(m0 + row) * 512 + it * 64 + sc8 * 8, As + seg * 1024);
            gload16(Wb + (size_t)(n0 + row) * 512 + it * 64 + sc8 * 8, Bs + seg * 1024);
        }
    };

    floatx4 acc[4][4];
#pragma unroll
    for (int a = 0; a < 4; ++a)
#pragma unroll
        for (int bb = 0; bb < 4; ++bb) acc[a][bb] = (floatx4){0.f, 0.f, 0.f, 0.f};

    stage(0, 0);
    __syncthreads();   // tile 0 staged

    for (int it = 0; it < 8; ++it) {
        if (it < 7) stage(it + 1, (it + 1) & 1);   // covered by compute below
        char* As = base + (it & 1) * 32768;
        char* Bs = As + 16384;
#pragma unroll
        for (int kst = 0; kst < 2; ++kst) {
            bf16x8 afr[4], bfr[4];
#pragma unroll
            for (int mt = 0; mt < 4; ++mt)
                afr[mt] = *(const bf16x8*)(As + (wm + mt * 16 + lane16) * 128 +
                                           ((kst * 4 + lq) ^ klo) * 16);
#pragma unroll
            for (int nt = 0; nt < 4; ++nt)
                bfr[nt] = *(const bf16x8*)(Bs + (wn + nt * 16 + lane16) * 128 +
                                           ((kst * 4 + lq) ^ klo) * 16);
#pragma unroll
            for (int mt = 0; mt < 4; ++mt)
#pragma unroll
                for (int nt = 0; nt < 4; ++nt)
                    acc[mt][nt] = MFMA16(afr[mt], bfr[nt], acc[mt][nt]);
        }
        __syncthreads();   // stage(it+1) ready; reads of buf(it) done
    }

    float bias_v[4];
#pragma unroll
    for (int nt = 0; nt < 4; ++nt) bias_v[nt] = biasc[n0 + wn + nt * 16 + lane16];

    if (n0 < 1024) {
        bf16_t* Dst = (n0 < 512) ? Q : K;
        const int coff = (n0 < 512 ? n0 : n0 - 512) + wn;
#pragma unroll
        for (int mt = 0; mt < 4; ++mt)
#pragma unroll
            for (int nt = 0; nt < 4; ++nt)
#pragma unroll
                for (int i = 0; i < 4; ++i) {
                    int rowM = m0 + wm + mt * 16 + lq * 4 + i;
                    Dst[(size_t)rowM * 512 + coff + nt * 16 + lane16] =
                        (bf16_t)(acc[mt][nt][i] + bias_v[nt]);
                }
    } else {
        // V: transpose through LDS (Vtile aliases the staging buffers; all
        // MFMA reads drained by the final loop sync above).
#pragma unroll
        for (int mt = 0; mt < 4; ++mt)
#pragma unroll
            for (int nt = 0; nt < 4; ++nt)
#pragma unroll
                for (int i = 0; i < 4; ++i) {
                    int dl = wn + nt * 16 + lane16;
                    int sl = wm + mt * 16 + lq * 4 + i;
                    *(bf16_t*)(Vtile + dl * 264 + sl * 2) =
                        (bf16_t)(acc[mt][nt][i] + bias_v[nt]);
                }
        __syncthreads();
        const int bb = m0 >> 11, s0 = m0 & 2047, dbase = n0 - 1024;
#pragma unroll
        for (int j = 0; j < 8; ++j) {
            int slot = j * 256 + tid;
            int dd = slot >> 4, c = slot & 15;
            *(int4*)(Vt + (size_t)(bb * 512 + dbase + dd) * 2048 + s0 + c * 8) =
                *(const int4*)(Vtile + dd * 264 + c * 16);
        }
    }
}

// ---------------------------------------------------------------------------
// Kernel 3: flash attention v7 + residual (proven best: ~107us). 256 blocks
// (b = bid&7 -> XCD affinity), 512 threads = 8 waves. Block = 64 q-rows,
// KVBLK = 32 keys, 64 kt, Ks/Vs double-buffered, staged a FULL iter ahead.
//  QK^T: wave (qg = w>>1, h = w&1) computes S[16 q][16-key half], Q in regs,
//        K frags from swizzled LDS.
//  softmax: p = exp(s) (no max shift), P -> LDS (80 B row stride),
//        l = running sum. Published by raw lgkmcnt(0)+s_barrier.
//  PV:   wave w owns d-slice w*64..+64 for ALL 64 q rows; V frags from
//        swizzled LDS; P read back as A-frags. __syncthreads at end of kt.
// ---------------------------------------------------------------------------
__global__ __launch_bounds__(512, 2)
void flash_attn_v7(const bf16_t* __restrict__ Q, const bf16_t* __restrict__ K,
                   const bf16_t* __restrict__ Vt, const float* __restrict__ X,
                   float* __restrict__ Out) {
    extern __shared__ char smem[];
    // Ks[buf] = smem + buf*32768            (32 keys x 64 chunks(16B), swizzled)
    // Vs[buf] = smem + 65536 + buf*32768    (256 d-pairs x 8 slots(16B), swizzled)
    char* Ps = smem + 131072;                // 5120: 64 rows x 80 B (64 data + 16 pad)
    float* lpart = (float*)(smem + 136192);  // 64 rows x 2 halves

    const int tid = threadIdx.x;
    const int l = tid & 63, w = tid >> 6;
    const int lane16 = l & 15, lq = l >> 4;
    const int qg = w >> 1, h = w & 1;          // QK^T role: 16q x 16keys
    const int dbase = w << 6;                  // PV d-slice
    const int b = blockIdx.x & 7;
    const int q0 = (blockIdx.x >> 3) << 6;

    const bf16_t* Kbase = K + (size_t)b * 2048 * 512;
    const bf16_t* Vbase = Vt + (size_t)b * 512 * 2048;

    // per-lane staging constants
    const int dl_v = ((l >> 3) << 1) | ((l & 7) >> 2);   // within-seg d offset
    const int vc   = (l & 3) ^ ((l >> 3) & 3);           // source chunk for V

    // stage K tile kt (32 keys x 1KB rows; 4 segs/wave; chunk swz ^key)
    auto stageK = [&](int kt, char* Kb) {
#pragma unroll
        for (int j = 0; j < 4; ++j) {
            int seg = j * 8 + w;                          // key 0..31
            int c = (l & ~7) | ((l & 7) ^ (seg & 7));
            gload16(Kbase + ((size_t)kt * 32 + seg) * 512 + c * 8, Kb + seg * 1024);
        }
    };
    // stage V tile kt ([256 d-pairs][8 slots]; 4 segs/wave; seg = 16 d-rows)
    auto stageV = [&](int kt, char* Vb) {
        const bf16_t* Vsrc = Vbase + kt * 32;
#pragma unroll
        for (int j = 0; j < 4; ++j) {
            int seg = j * 8 + w;
            int d = seg * 16 + dl_v;
            gload16(Vsrc + (size_t)d * 2048 + vc * 8, Vb + seg * 1024);
        }
    };

    stageK(0, smem);
    stageV(0, smem + 65536);

    // Q fragments: A[m=lane16][k=lq*8+...] for rows q0+qg*16..+16
    bf16x8 qf[16];
    const bf16_t* Qrow = Q + (size_t)(b * 2048 + q0 + qg * 16 + lane16) * 512 + lq * 8;
#pragma unroll
    for (int kst = 0; kst < 16; ++kst) qf[kst] = *(const bf16x8*)(Qrow + kst * 32);

    floatx4 o[16];                     // [qgi][dg]: rows qgi*16.., cols dbase+dg*16..
#pragma unroll
    for (int t = 0; t < 16; ++t) o[t] = (floatx4){0.f, 0.f, 0.f, 0.f};
    float lsum[4] = {0.f, 0.f, 0.f, 0.f};   // per-lane partial row sums
    const float L2E = 1.4426950408889634f;
    const int key = h * 16 + lane16;         // this wave's key column

    __syncthreads();   // K_0/V_0 staged (full drain: prologue only)

    for (int kt = 0; kt < 64; ++kt) {
        char* Kcur = smem + (kt & 1) * 32768;
        char* Vcur = smem + 65536 + (kt & 1) * 32768;

        // issue kt+1 staging into the other buffers; consumed next iteration,
        // drained by next __syncthreads -> a full body of latency cover.
        if (kt < 63) {
            stageK(kt + 1, smem + ((kt + 1) & 1) * 32768);
            stageV(kt + 1, smem + 65536 + ((kt + 1) & 1) * 32768);
        }

        // ---- QK^T: 16 q rows x 16 keys, k=512 ----
        floatx4 sc = (floatx4){0.f, 0.f, 0.f, 0.f};
#pragma unroll
        for (int kst = 0; kst < 16; ++kst) {
            int i0 = kst * 4 + lq;
            int p0 = (i0 & ~7) | ((i0 & 7) ^ (key & 7));
            bf16x8 kb = *(const bf16x8*)(Kcur + key * 1024 + p0 * 16);
            sc = MFMA16(qf[kst], kb, sc);
        }

        // ---- softmax (no max shift): p = exp(s), write P, accumulate l ----
#pragma unroll
        for (int i = 0; i < 4; ++i) {
            int row = qg * 16 + lq * 4 + i;
            float p = __builtin_exp2f(sc[i] * L2E);
            lsum[i] += p;
            *(bf16_t*)(Ps + row * 80 + key * 2) = (bf16_t)p;
        }

        // barrier 1: publish P only; staging DMAs stay in flight (no vmcnt).
        asm volatile("s_waitcnt lgkmcnt(0)\n\ts_barrier" ::: "memory");
        __builtin_amdgcn_sched_barrier(0);

        // ---- PV: O[64 q x 64 d slice] += P[64x32] * V^T ----
        bf16x8 pa[4], vb[4];
#pragma unroll
        for (int qgi = 0; qgi < 4; ++qgi)
            pa[qgi] = *(const bf16x8*)(Ps + (qgi * 16 + lane16) * 80 + lq * 16);
#pragma unroll
        for (int dg = 0; dg < 4; ++dg) {
            int d = dbase + dg * 16 + lane16;
            int slot = (d & 1) * 4 + (lq ^ ((d >> 1) & 3));
            vb[dg] = *(const bf16x8*)(Vcur + (d >> 1) * 128 + slot * 16);
        }
#pragma unroll
        for (int dg = 0; dg < 4; ++dg)
#pragma unroll
            for (int qgi = 0; qgi < 4; ++qgi)
                o[qgi * 4 + dg] = MFMA16(pa[qgi], vb[dg], o[qgi * 4 + dg]);

        __syncthreads();   // barrier 2: kt+1 staged (DMAs a full body old),
                           // Ps free for rewrite, buffers swap.
    }

    // epilogue: reduce l across lane16 and key-halves, normalize, + residual
#pragma unroll
    for (int i = 0; i < 4; ++i) {
        float s = wave16_sum(lsum[i]);
        if (lane16 == 0) lpart[(qg * 16 + lq * 4 + i) * 2 + h] = s;
    }
    __syncthreads();

#pragma unroll
    for (int qgi = 0; qgi < 4; ++qgi) {
        float rinv[4];
#pragma unroll
        for (int i = 0; i < 4; ++i) {
            int row = qgi * 16 + lq * 4 + i;
            rinv[i] = 1.0f / (lpart[row * 2] + lpart[row * 2 + 1]);
        }
#pragma unroll
        for (int dg = 0; dg < 4; ++dg) {
            int d = dbase + dg * 16 + lane16;
#pragma unroll
            for (int i = 0; i < 4; ++i) {
                int row = q0 + qgi * 16 + lq * 4 + i;
                size_t g = (size_t)(b * 2048 + row) * 512 + d;
                Out[g] = o[qgi * 4 + dg][i] * rinv[i] + X[g];
            }
        }
    }
}

// ---------------------------------------------------------------------------
extern "C" void kernel_launch(void* const* d_in, const int* in_sizes, int n_in,
                              void* d_out, int out_size, void* d_ws, size_t ws_size,
                              hipStream_t stream) {
    const float* x  = (const float*)d_in[0];
    const float* Wq = (const float*)d_in[1];
    const float* bq = (const float*)d_in[2];
    const float* Wk = (const float*)d_in[3];
    const float* bk = (const float*)d_in[4];
    const float* Wv = (const float*)d_in[5];
    const float* bv = (const float*)d_in[6];
    float* out = (float*)d_out;
    char* ws = (char*)d_ws;

    bf16_t* Wb    = (bf16_t*)(ws);
    float*  biasc = (float*)(ws + 1572864);
    bf16_t* Xb    = (bf16_t*)(ws + 1579008);
    bf16_t* Qb    = (bf16_t*)(ws + 18356224);
    bf16_t* Kb    = (bf16_t*)(ws + 35133440);
    bf16_t* Vt    = (bf16_t*)(ws + 51910656);
    // total ws use: 68,687,872 B

    convert_in<<<4864, 256, 0, stream>>>(x, Wq, Wk, Wv, bq, bk, bv, Xb, Wb, biasc);
    qkv_gemm<<<1536, 256, 0, stream>>>(Xb, Wb, biasc, Qb, Kb, Vt);

    hipFuncSetAttribute(reinterpret_cast<const void*>(flash_attn_v7),
                        hipFuncAttributeMaxDynamicSharedMemorySize, FLASH_LDS);
    flash_attn_v7<<<256, 512, FLASH_LDS, stream>>>(Qb, Kb, Vt, x, out);
}